// Round 3
// baseline (160.759 us; speedup 1.0000x reference)
//
#include <hip/hip_runtime.h>
#include <hip/hip_bf16.h>

typedef __attribute__((ext_vector_type(8))) short bf16x8;
typedef __attribute__((ext_vector_type(4))) float f32x4;
typedef __attribute__((ext_vector_type(4))) float fvec4;
typedef __attribute__((ext_vector_type(8))) unsigned short u16x8;

// B=4, T=256, U=64 -> M = 65536 rows; K(J)=512; N(V)=1024

__device__ __forceinline__ unsigned short f2bf(float f) {
  unsigned int u = __builtin_bit_cast(unsigned int, f);
  u += 0x7FFFu + ((u >> 16) & 1u);   // round-to-nearest-even
  return (unsigned short)(u >> 16);
}

__device__ __forceinline__ float fast_tanh(float x) {
  float cx = fminf(fmaxf(x, -9.0f), 9.0f);
  float e2 = __expf(cx + cx);
  return (e2 - 1.0f) * __builtin_amdgcn_rcpf(e2 + 1.0f);
}

// ---- fused prep: enc-proj (blocks 0..127), pred-proj (128..159), W_out^T (160..287)

__device__ __forceinline__ void proj_body(
    const float* __restrict__ x, const float* __restrict__ W,
    const float* __restrict__ bias, float* __restrict__ out,
    int blk, uint8_t* sh) {
  float (*xt)[9] = (float (*)[9])sh;   // [256][9] f32 = 9216 B
  const int tid = threadIdx.x;
  const int row0 = blk << 3;
  #pragma unroll
  for (int i = 0; i < 8; ++i)
    xt[tid][i] = x[(size_t)(row0 + i) * 256 + tid];
  __syncthreads();
  float acc0[8] = {0.f,0.f,0.f,0.f,0.f,0.f,0.f,0.f};
  float acc1[8] = {0.f,0.f,0.f,0.f,0.f,0.f,0.f,0.f};
  #pragma unroll 4
  for (int k = 0; k < 256; ++k) {
    float w0 = W[(size_t)k * 512 + tid];
    float w1 = W[(size_t)k * 512 + tid + 256];
    #pragma unroll
    for (int r = 0; r < 8; ++r) {
      float xv = xt[k][r];
      acc0[r] = fmaf(xv, w0, acc0[r]);
      acc1[r] = fmaf(xv, w1, acc1[r]);
    }
  }
  float b0 = bias[tid], b1 = bias[tid + 256];
  #pragma unroll
  for (int r = 0; r < 8; ++r) {
    out[(size_t)(row0 + r) * 512 + tid]       = acc0[r] + b0;
    out[(size_t)(row0 + r) * 512 + tid + 256] = acc1[r] + b1;
  }
}

__device__ __forceinline__ void transpose_body(
    const float* __restrict__ W, unsigned short* __restrict__ Wt,
    int blk, uint8_t* sh) {
  unsigned short (*tile)[65] = (unsigned short (*)[65])sh;  // [64][65] = 8320 B
  const int k0 = (blk & 7) << 6;
  const int n0 = (blk >> 3) << 6;
  const int tid = threadIdx.x;
  #pragma unroll
  for (int i = 0; i < 16; ++i) {
    int idx = tid + (i << 8);
    int r = idx >> 6, c = idx & 63;
    tile[r][c] = f2bf(W[(size_t)(k0 + r) * 1024 + n0 + c]);
  }
  __syncthreads();
  #pragma unroll
  for (int i = 0; i < 16; ++i) {
    int idx = tid + (i << 8);
    int r = idx >> 6, c = idx & 63;
    Wt[(size_t)(n0 + r) * 512 + k0 + c] = tile[c][r];
  }
}

__global__ __launch_bounds__(256) void prep_kernel(
    const float* __restrict__ enc, const float* __restrict__ We,
    const float* __restrict__ be, float* __restrict__ encp,
    const float* __restrict__ pred, const float* __restrict__ Wd,
    const float* __restrict__ bd, float* __restrict__ predp,
    const float* __restrict__ Wo, unsigned short* __restrict__ Wt) {
  __shared__ uint8_t sh[9216];
  const int b = blockIdx.x;
  if (b < 128)       proj_body(enc, We, be, encp, b, sh);
  else if (b < 160)  proj_body(pred, Wd, bd, predp, b - 128, sh);
  else               transpose_body(Wo, Wt, b - 160, sh);
}

// ---- joint: A[m][k] = bf16(tanh(encp[m>>6][k] + predp[b*64 + (m&63)][k]))

__global__ __launch_bounds__(256) void joint_kernel(
    const float* __restrict__ encp, const float* __restrict__ predp,
    unsigned short* __restrict__ A) {
  int vid = blockIdx.x * 256 + threadIdx.x;   // 65536 rows * 64 chunks
  int m = vid >> 6;
  int k8 = (vid & 63) << 3;
  const float* e = encp + ((size_t)(m >> 6) << 9) + k8;
  const float* p = predp + ((size_t)(((m >> 14) << 6) | (m & 63)) << 9) + k8;
  fvec4 e0 = *(const fvec4*)e;
  fvec4 e1 = *(const fvec4*)(e + 4);
  fvec4 p0 = *(const fvec4*)p;
  fvec4 p1 = *(const fvec4*)(p + 4);
  u16x8 o;
  #pragma unroll
  for (int i = 0; i < 4; ++i) o[i]     = f2bf(fast_tanh(e0[i] + p0[i]));
  #pragma unroll
  for (int i = 0; i < 4; ++i) o[i + 4] = f2bf(fast_tanh(e1[i] + p1[i]));
  *(u16x8*)(A + ((size_t)m << 9) + k8) = o;
}

// ---- gemm: C[m][n] = sum_k A[m][k]*Bt[n][k] + bout[n]
// 256x256 tile, BK=32, 8 waves (2Mx4N), per-wave 128x64 = 8x4 frags.
// 4 K-tile LDS slots (128 KiB), prefetch distance 2, counted vmcnt(4) at tile
// boundaries (never 0 in steady state). 2 phases/tile, fine interleave
// ds_read || global_load_lds || MFMA, setprio around MFMA clusters.
// MFMA operands swapped: lane holds C[m=lane&15-dim][n=reg-dim] -> dwordx4 stores.
__global__ __launch_bounds__(512) void gemm_kernel(
    const unsigned short* __restrict__ A, const unsigned short* __restrict__ Bt,
    const float* __restrict__ bout, float* __restrict__ out) {
  __shared__ uint8_t lds[4][2][16384];   // [slot][A/B][256 rows x 32 bf16 (64B rows)]
  const int b = blockIdx.x;
  const int wg = ((b & 7) << 7) + (b >> 3);   // XCD swizzle, 1024 % 8 == 0 (bijective)
  const int mt = wg >> 2, nt = wg & 3;        // nt inner: 4 consecutive wg share A-panel
  const int m0 = mt << 8, n0 = nt << 8;
  const int tid = threadIdx.x;
  const int lane = tid & 63, wid = tid >> 6;
  const int wm = wid >> 2, wn = wid & 3;      // 2 x 4 wave grid
  const int fr = lane & 15, fg = lane >> 4;

  // staging addresses: chunk c = (r*8+wid)*64 + lane covers 1024 x 16B chunks
  const unsigned short* gAr[2];
  const unsigned short* gBr[2];
  #pragma unroll
  for (int r = 0; r < 2; ++r) {
    int c = ((r * 8 + wid) << 6) + lane;
    int row = c >> 2, kc = (c & 3) << 3;
    gAr[r] = A  + (size_t)(m0 + row) * 512 + kc;
    gBr[r] = Bt + (size_t)(n0 + row) * 512 + kc;
  }

  auto stageA = [&](int kt) {
    uint8_t* base = &lds[kt & 3][0][0];
    #pragma unroll
    for (int r = 0; r < 2; ++r)
      __builtin_amdgcn_global_load_lds(
          (const __attribute__((address_space(1))) void*)(gAr[r] + (kt << 5)),
          (__attribute__((address_space(3))) void*)(base + ((r * 8 + wid) << 10)),
          16, 0, 0);
  };
  auto stageB = [&](int kt) {
    uint8_t* base = &lds[kt & 3][1][0];
    #pragma unroll
    for (int r = 0; r < 2; ++r)
      __builtin_amdgcn_global_load_lds(
          (const __attribute__((address_space(1))) void*)(gBr[r] + (kt << 5)),
          (__attribute__((address_space(3))) void*)(base + ((r * 8 + wid) << 10)),
          16, 0, 0);
  };

  f32x4 acc[8][4];
  f32x4 zero4 = {0.f, 0.f, 0.f, 0.f};
  #pragma unroll
  for (int i = 0; i < 8; ++i)
    #pragma unroll
    for (int j = 0; j < 4; ++j) acc[i][j] = zero4;

  // prologue: tiles 0 and 1 in flight (8 loads)
  stageA(0); stageB(0); stageA(1); stageB(1);

  const int aoff = (((wm << 7) + fr) << 6) + (fg << 4);  // (wm*128+fr)*64 + fg*16
  const int boff = (((wn << 6) + fr) << 6) + (fg << 4);  // (wn*64 +fr)*64 + fg*16

  for (int t = 0; t < 16; ++t) {
    const uint8_t* sA = &lds[t & 3][0][0];
    const uint8_t* sB = &lds[t & 3][1][0];
    // tile-boundary: tile t landed; tile t+1's 4 loads may stay in flight
    if (t < 15) asm volatile("s_waitcnt vmcnt(4)" ::: "memory");
    else        asm volatile("s_waitcnt vmcnt(0)" ::: "memory");
    __builtin_amdgcn_s_barrier();

    // ---- phase 1: frags (A lo-half + all B) | stage A(t+2) | MFMA quadrant
    bf16x8 af[4], bfv[4];
    #pragma unroll
    for (int i = 0; i < 4; ++i)
      af[i] = *(const bf16x8*)(sA + aoff + (i << 10));
    #pragma unroll
    for (int j = 0; j < 4; ++j)
      bfv[j] = *(const bf16x8*)(sB + boff + (j << 10));
    if (t < 14) stageA(t + 2);
    __builtin_amdgcn_s_barrier();
    asm volatile("s_waitcnt lgkmcnt(0)" ::: "memory");
    __builtin_amdgcn_sched_barrier(0);
    __builtin_amdgcn_s_setprio(1);
    #pragma unroll
    for (int i = 0; i < 4; ++i)
      #pragma unroll
      for (int j = 0; j < 4; ++j)
        acc[i][j] = __builtin_amdgcn_mfma_f32_16x16x32_bf16(bfv[j], af[i],
                                                            acc[i][j], 0, 0, 0);
    __builtin_amdgcn_s_setprio(0);
    __builtin_amdgcn_s_barrier();

    // ---- phase 2: frags (A hi-half, reuse B) | stage B(t+2) | MFMA quadrant
    bf16x8 ah[4];
    #pragma unroll
    for (int i = 0; i < 4; ++i)
      ah[i] = *(const bf16x8*)(sA + aoff + ((i + 4) << 10));
    if (t < 14) stageB(t + 2);
    __builtin_amdgcn_s_barrier();
    asm volatile("s_waitcnt lgkmcnt(0)" ::: "memory");
    __builtin_amdgcn_sched_barrier(0);
    __builtin_amdgcn_s_setprio(1);
    #pragma unroll
    for (int i = 0; i < 4; ++i)
      #pragma unroll
      for (int j = 0; j < 4; ++j)
        acc[i + 4][j] = __builtin_amdgcn_mfma_f32_16x16x32_bf16(bfv[j], ah[i],
                                                                acc[i + 4][j], 0, 0, 0);
    __builtin_amdgcn_s_setprio(0);
    // trailing barrier = next iteration's opening barrier
  }

  // epilogue: frag (mf,nf): C[m0+wm*128+mf*16+fr][n0+wn*64+nf*16+fg*4 .. +3]
  #pragma unroll
  for (int nf = 0; nf < 4; ++nf) {
    const int gn = n0 + (wn << 6) + (nf << 4) + (fg << 2);
    const fvec4 bv = *(const fvec4*)&bout[gn];
    #pragma unroll
    for (int mf = 0; mf < 8; ++mf) {
      const int gm = m0 + (wm << 7) + (mf << 4) + fr;
      fvec4 o = acc[mf][nf] + bv;
      *(fvec4*)&out[(size_t)gm * 1024 + gn] = o;
    }
  }
}

extern "C" void kernel_launch(void* const* d_in, const int* in_sizes, int n_in,
                              void* d_out, int out_size, void* d_ws, size_t ws_size,
                              hipStream_t stream) {
  const float* enc   = (const float*)d_in[0];
  const float* pred  = (const float*)d_in[1];
  const float* W_enc = (const float*)d_in[2];
  const float* b_enc = (const float*)d_in[3];
  const float* W_dec = (const float*)d_in[4];
  const float* b_dec = (const float*)d_in[5];
  const float* W_out = (const float*)d_in[6];
  const float* b_out = (const float*)d_in[7];
  float* out = (float*)d_out;

  uint8_t* ws = (uint8_t*)d_ws;
  float* encp  = (float*)ws;                           // [1024][512] f32, 2 MiB
  float* predp = (float*)(ws + 2097152);               // [256][512]  f32, 0.5 MiB
  unsigned short* wt = (unsigned short*)(ws + 2621440);// [1024][512] bf16, 1 MiB
  unsigned short* Aj = (unsigned short*)(ws + 3670016);// [65536][512] bf16, 64 MiB

  prep_kernel<<<288, 256, 0, stream>>>(enc, W_enc, b_enc, encp,
                                       pred, W_dec, b_dec, predp,
                                       W_out, wt);
  joint_kernel<<<16384, 256, 0, stream>>>(encp, predp, Aj);
  gemm_kernel<<<1024, 512, 0, stream>>>(Aj, wt, b_out, out);
}